// Round 4
// baseline (134.803 us; speedup 1.0000x reference)
//
#include <hip/hip_runtime.h>
#include <math.h>

typedef unsigned short ushort_t;
typedef __bf16   bf16x8  __attribute__((ext_vector_type(8)));
typedef float    floatx4 __attribute__((ext_vector_type(4)));
typedef ushort_t ushortx8 __attribute__((ext_vector_type(8)));

__device__ __forceinline__ float bf2f(ushort_t u) {
    unsigned int x = ((unsigned int)u) << 16;
    return __builtin_bit_cast(float, x);
}
__device__ __forceinline__ ushort_t f2bf(float f) {
    unsigned int x = __builtin_bit_cast(unsigned int, f);
    x += 0x7fffu + ((x >> 16) & 1u);   // RNE
    return (ushort_t)(x >> 16);
}
__device__ __forceinline__ __bf16 f2bf16t(float f) {
    ushort_t u = f2bf(f);
    return __builtin_bit_cast(__bf16, u);
}

// N3R fused PE + 3-layer MLP.  Inputs: f32 (harness upcasts the f16 ref
// tensors).  Output: f32.  One wave = 16 points/iter via mfma 16x16x32_bf16.
// Weights are hi/lo-split into two bf16 fragments (w = hi + lo) so weight
// rounding error ~2^-17; activations are single bf16 (error ~2^-9, well under
// the 2%-of-absmax threshold).
__global__ __launch_bounds__(256) void nerf_fused_kernel(
    const float* __restrict__ coords,
    const float* __restrict__ W1, const float* __restrict__ b1,
    const float* __restrict__ W2, const float* __restrict__ b2,
    const float* __restrict__ W3, const float* __restrict__ b3,
    float* __restrict__ out, int npts)
{
    // per-wave [16 rows][64+8 pad cols] bf16 tile (2304 B each, 9216 B/block)
    __shared__ __align__(16) ushort_t h_s[4][16][72];

    const int tid  = threadIdx.x;
    const int wave = tid >> 6;
    const int lane = tid & 63;
    const int m    = lane & 15;       // MFMA row (A) / col (B,D)
    const int g    = lane >> 4;       // quarter-wave group
    const int kb   = g * 8;           // this lane's K-base within a K=32 chunk

    // ---------------- weight fragments (hi/lo split, in registers) --------
    // B-frag layout: lane holds B[k = kb+i][n = t*16 + (lane&15)]
    bf16x8 B1h[4], B1l[4];
    #pragma unroll
    for (int t = 0; t < 4; ++t) {
        #pragma unroll
        for (int i = 0; i < 8; ++i) {
            int k = kb + i;
            int n = t * 16 + m;
            float w = (k < 27) ? W1[k * 64 + n] : 0.f;
            ushort_t hi = f2bf(w);
            B1h[t][i] = __builtin_bit_cast(__bf16, hi);
            B1l[t][i] = f2bf16t(w - bf2f(hi));
        }
    }
    bf16x8 B2h[2][4], B2l[2][4];   // [k-chunk][n-tile]
    #pragma unroll
    for (int kk = 0; kk < 2; ++kk) {
        #pragma unroll
        for (int t = 0; t < 4; ++t) {
            #pragma unroll
            for (int i = 0; i < 8; ++i) {
                int k = kk * 32 + kb + i;
                int n = t * 16 + m;
                float w = W2[k * 64 + n];
                ushort_t hi = f2bf(w);
                B2h[kk][t][i] = __builtin_bit_cast(__bf16, hi);
                B2l[kk][t][i] = f2bf16t(w - bf2f(hi));
            }
        }
    }
    bf16x8 B3h[2], B3l[2];         // N padded 4 -> 16 with zeros
    #pragma unroll
    for (int kk = 0; kk < 2; ++kk) {
        #pragma unroll
        for (int i = 0; i < 8; ++i) {
            int k = kk * 32 + kb + i;
            float w = (m < 4) ? W3[k * 4 + m] : 0.f;
            ushort_t hi = f2bf(w);
            B3h[kk][i] = __builtin_bit_cast(__bf16, hi);
            B3l[kk][i] = f2bf16t(w - bf2f(hi));
        }
    }
    float bias1[4], bias2[4];
    #pragma unroll
    for (int t = 0; t < 4; ++t) {
        bias1[t] = b1[t * 16 + m];
        bias2[t] = b2[t * 16 + m];
    }
    const float bias3 = (m < 4) ? b3[m] : 0.f;

    // ---------------- main loop: 16 points per wave-iteration -------------
    // nt16 % nw == 0 -> all waves run identical trip counts -> barriers legal
    const int nt16 = npts >> 4;
    const int gw   = blockIdx.x * 4 + wave;
    const int nw   = gridDim.x * 4;

    for (int t16 = gw; t16 < nt16; t16 += nw) {
        const int pbase = t16 << 4;

        const long cbase = (long)(pbase + m) * 3;
        const float x0 = coords[cbase + 0];
        const float x1 = coords[cbase + 1];
        const float x2 = coords[cbase + 2];

        // ---- positional encoding: this lane's 8 enc features kb..kb+7 ----
        // enc[j]: j<3 -> x_j ; j-3 = l*6 + s*3 + c -> (s? cos : sin)(x_c * 2^l)
        bf16x8 a1;
        #pragma unroll
        for (int i = 0; i < 8; ++i) {
            int j = kb + i;
            float v;
            if (j < 3) {
                v = (j == 0) ? x0 : ((j == 1) ? x1 : x2);
            } else if (j < 27) {
                int mm  = j - 3;
                int lv  = mm / 6;
                int rem = mm - lv * 6;
                int sfl = (rem >= 3);
                int c   = rem - (sfl ? 3 : 0);
                float xv  = (c == 0) ? x0 : ((c == 1) ? x1 : x2);
                float arg = xv * (float)(1 << lv);
                float sv, cv;
                __sincosf(arg, &sv, &cv);
                v = sfl ? cv : sv;
            } else {
                v = 0.f;
            }
            a1[i] = f2bf16t(v);
        }

        // ---------------- layer 1: enc(16x32) @ W1(32x64) ----------------
        floatx4 acc1[4];
        #pragma unroll
        for (int t = 0; t < 4; ++t) acc1[t] = (floatx4){0.f, 0.f, 0.f, 0.f};
        #pragma unroll
        for (int t = 0; t < 4; ++t) {
            acc1[t] = __builtin_amdgcn_mfma_f32_16x16x32_bf16(a1, B1h[t], acc1[t], 0, 0, 0);
            acc1[t] = __builtin_amdgcn_mfma_f32_16x16x32_bf16(a1, B1l[t], acc1[t], 0, 0, 0);
        }

        // relu(+bias) -> LDS rows (D layout: row = g*4+r, col = t*16+m)
        #pragma unroll
        for (int t = 0; t < 4; ++t) {
            #pragma unroll
            for (int r = 0; r < 4; ++r) {
                float v = acc1[t][r] + bias1[t];
                v = v > 0.f ? v : 0.f;
                h_s[wave][g * 4 + r][t * 16 + m] = f2bf(v);
            }
        }
        __syncthreads();

        // ---------------- layer 2: h1(16x64) @ W2(64x64) ------------------
        bf16x8 a2[2];
        #pragma unroll
        for (int kk = 0; kk < 2; ++kk) {
            ushortx8 u = *reinterpret_cast<const ushortx8*>(&h_s[wave][m][kk * 32 + kb]);
            a2[kk] = __builtin_bit_cast(bf16x8, u);
        }
        floatx4 acc2[4];
        #pragma unroll
        for (int t = 0; t < 4; ++t) acc2[t] = (floatx4){0.f, 0.f, 0.f, 0.f};
        #pragma unroll
        for (int kk = 0; kk < 2; ++kk) {
            #pragma unroll
            for (int t = 0; t < 4; ++t) {
                acc2[t] = __builtin_amdgcn_mfma_f32_16x16x32_bf16(a2[kk], B2h[kk][t], acc2[t], 0, 0, 0);
                acc2[t] = __builtin_amdgcn_mfma_f32_16x16x32_bf16(a2[kk], B2l[kk][t], acc2[t], 0, 0, 0);
            }
        }

        __syncthreads();   // h1 reads done before overwrite with h2

        #pragma unroll
        for (int t = 0; t < 4; ++t) {
            #pragma unroll
            for (int r = 0; r < 4; ++r) {
                float v = acc2[t][r] + bias2[t];
                v = v > 0.f ? v : 0.f;
                h_s[wave][g * 4 + r][t * 16 + m] = f2bf(v);
            }
        }
        __syncthreads();

        // ---------------- layer 3: h2(16x64) @ W3(64x16 padded) -----------
        bf16x8 a3[2];
        #pragma unroll
        for (int kk = 0; kk < 2; ++kk) {
            ushortx8 u = *reinterpret_cast<const ushortx8*>(&h_s[wave][m][kk * 32 + kb]);
            a3[kk] = __builtin_bit_cast(bf16x8, u);
        }
        floatx4 acc3 = (floatx4){0.f, 0.f, 0.f, 0.f};
        #pragma unroll
        for (int kk = 0; kk < 2; ++kk) {
            acc3 = __builtin_amdgcn_mfma_f32_16x16x32_bf16(a3[kk], B3h[kk], acc3, 0, 0, 0);
            acc3 = __builtin_amdgcn_mfma_f32_16x16x32_bf16(a3[kk], B3l[kk], acc3, 0, 0, 0);
        }

        __syncthreads();   // h2 reads done before staging overwrite

        // stage 16 points x 4 channels as f32, then coalesced 16B stores
        float* fstage = (float*)&h_s[wave][0][0];   // 2304 B/wave >= 256 B
        if (m < 4) {
            #pragma unroll
            for (int r = 0; r < 4; ++r)
                fstage[(g * 4 + r) * 4 + m] = acc3[r] + bias3;
        }
        __syncthreads();

        if (lane < 16) {
            floatx4 o = *reinterpret_cast<const floatx4*>(&fstage[lane * 4]);
            *reinterpret_cast<floatx4*>(&out[(long)(pbase + lane) * 4]) = o;
        }
        __syncthreads();   // staging reads done before next iter's L1 store
    }
}

extern "C" void kernel_launch(void* const* d_in, const int* in_sizes, int n_in,
                              void* d_out, int out_size, void* d_ws, size_t ws_size,
                              hipStream_t stream) {
    const float* coords = (const float*)d_in[0];
    const float* W1 = (const float*)d_in[1];
    const float* b1 = (const float*)d_in[2];
    const float* W2 = (const float*)d_in[3];
    const float* b2 = (const float*)d_in[4];
    const float* W3 = (const float*)d_in[5];
    const float* b3 = (const float*)d_in[6];
    float* outp = (float*)d_out;

    const int npts = in_sizes[0] / 3;           // 2,097,152
    const int nblocks = 2048;                   // 8192 waves; 131072 % 8192 == 0
    hipLaunchKernelGGL(nerf_fused_kernel, dim3(nblocks), dim3(256), 0, stream,
                       coords, W1, b1, W2, b2, W3, b3, outp, npts);
}

// Round 5
// 127.882 us; speedup vs baseline: 1.0541x; 1.0541x over previous
//
#include <hip/hip_runtime.h>
#include <math.h>

typedef unsigned short ushort_t;
typedef __bf16   bf16x8  __attribute__((ext_vector_type(8)));
typedef float    floatx4 __attribute__((ext_vector_type(4)));
typedef ushort_t ushortx8 __attribute__((ext_vector_type(8)));

__device__ __forceinline__ float bf2f(ushort_t u) {
    unsigned int x = ((unsigned int)u) << 16;
    return __builtin_bit_cast(float, x);
}
__device__ __forceinline__ ushort_t f2bf(float f) {
    unsigned int x = __builtin_bit_cast(unsigned int, f);
    x += 0x7fffu + ((x >> 16) & 1u);   // RNE
    return (ushort_t)(x >> 16);
}
__device__ __forceinline__ __bf16 f2bf16t(float f) {
    ushort_t u = f2bf(f);
    return __builtin_bit_cast(__bf16, u);
}
// same-wave LDS write->read fence (rule #18: asm waitcnt + sched_barrier)
__device__ __forceinline__ void lds_fence() {
    asm volatile("s_waitcnt lgkmcnt(0)" ::: "memory");
    __builtin_amdgcn_sched_barrier(0);
}

// N3R fused PE + 3-layer MLP.  Inputs f32 (harness upcasts f16), output f32.
// One wave = 16 points/iter via mfma_f32_16x16x32_bf16; hi/lo-split weights.
// LDS tiles are wave-private -> NO block barriers; wave-local fences only.
__global__ __launch_bounds__(256) void nerf_fused_kernel(
    const float* __restrict__ coords,
    const float* __restrict__ W1, const float* __restrict__ b1,
    const float* __restrict__ W2, const float* __restrict__ b2,
    const float* __restrict__ W3, const float* __restrict__ b3,
    float* __restrict__ out, int npts)
{
    // per-wave [16 rows][64+8 pad cols] bf16 tile (2304 B each, 9216 B/block)
    __shared__ __align__(16) ushort_t h_s[4][16][72];

    const int tid  = threadIdx.x;
    const int wave = tid >> 6;
    const int lane = tid & 63;
    const int m    = lane & 15;       // MFMA row (A) / col (B,D)
    const int g    = lane >> 4;       // quarter-wave group
    const int kb   = g * 8;           // this lane's K-base within a K=32 chunk

    // ---------------- weight fragments (hi/lo split, in registers) --------
    // B-frag layout: lane holds B[k = kb+i][n = t*16 + (lane&15)]
    bf16x8 B1h[4], B1l[4];
    #pragma unroll
    for (int t = 0; t < 4; ++t) {
        #pragma unroll
        for (int i = 0; i < 8; ++i) {
            int k = kb + i;
            int n = t * 16 + m;
            float w = (k < 27) ? W1[k * 64 + n] : 0.f;
            ushort_t hi = f2bf(w);
            B1h[t][i] = __builtin_bit_cast(__bf16, hi);
            B1l[t][i] = f2bf16t(w - bf2f(hi));
        }
    }
    bf16x8 B2h[2][4], B2l[2][4];   // [k-chunk][n-tile]
    #pragma unroll
    for (int kk = 0; kk < 2; ++kk) {
        #pragma unroll
        for (int t = 0; t < 4; ++t) {
            #pragma unroll
            for (int i = 0; i < 8; ++i) {
                int k = kk * 32 + kb + i;
                int n = t * 16 + m;
                float w = W2[k * 64 + n];
                ushort_t hi = f2bf(w);
                B2h[kk][t][i] = __builtin_bit_cast(__bf16, hi);
                B2l[kk][t][i] = f2bf16t(w - bf2f(hi));
            }
        }
    }
    bf16x8 B3h[2], B3l[2];         // N padded 4 -> 16 with zeros
    #pragma unroll
    for (int kk = 0; kk < 2; ++kk) {
        #pragma unroll
        for (int i = 0; i < 8; ++i) {
            int k = kk * 32 + kb + i;
            float w = (m < 4) ? W3[k * 4 + m] : 0.f;
            ushort_t hi = f2bf(w);
            B3h[kk][i] = __builtin_bit_cast(__bf16, hi);
            B3l[kk][i] = f2bf16t(w - bf2f(hi));
        }
    }
    float bias1[4], bias2[4];
    #pragma unroll
    for (int t = 0; t < 4; ++t) {
        bias1[t] = b1[t * 16 + m];
        bias2[t] = b2[t * 16 + m];
    }
    const float bias3 = (m < 4) ? b3[m] : 0.f;

    // ---------------- main loop: 16 points per wave-iteration -------------
    const int nt16 = npts >> 4;
    const int gw   = blockIdx.x * 4 + wave;
    const int nw   = gridDim.x * 4;

    for (int t16 = gw; t16 < nt16; t16 += nw) {
        const int pbase = t16 << 4;

        const long cbase = (long)(pbase + m) * 3;
        const float x0 = coords[cbase + 0];
        const float x1 = coords[cbase + 1];
        const float x2 = coords[cbase + 2];

        // ---- positional encoding: this lane's 8 enc features kb..kb+7 ----
        // enc[j]: j<3 -> x_j ; j-3 = l*6 + s*3 + c -> (s? cos : sin)(x_c * 2^l)
        bf16x8 a1;
        #pragma unroll
        for (int i = 0; i < 8; ++i) {
            int j = kb + i;
            float v;
            if (j < 3) {
                v = (j == 0) ? x0 : ((j == 1) ? x1 : x2);
            } else if (j < 27) {
                int mm  = j - 3;
                int lv  = mm / 6;
                int rem = mm - lv * 6;
                int sfl = (rem >= 3);
                int c   = rem - (sfl ? 3 : 0);
                float xv  = (c == 0) ? x0 : ((c == 1) ? x1 : x2);
                float arg = xv * (float)(1 << lv);
                float sv, cv;
                __sincosf(arg, &sv, &cv);
                v = sfl ? cv : sv;
            } else {
                v = 0.f;
            }
            a1[i] = f2bf16t(v);
        }

        // ---------------- layer 1: enc(16x32) @ W1(32x64) ----------------
        floatx4 acc1[4];
        #pragma unroll
        for (int t = 0; t < 4; ++t) {
            float b = bias1[t];
            acc1[t] = (floatx4){b, b, b, b};     // bias folded into acc init
        }
        #pragma unroll
        for (int t = 0; t < 4; ++t) {
            acc1[t] = __builtin_amdgcn_mfma_f32_16x16x32_bf16(a1, B1h[t], acc1[t], 0, 0, 0);
            acc1[t] = __builtin_amdgcn_mfma_f32_16x16x32_bf16(a1, B1l[t], acc1[t], 0, 0, 0);
        }

        // relu -> LDS rows (D layout: row = g*4+r, col = t*16+m)
        #pragma unroll
        for (int t = 0; t < 4; ++t) {
            #pragma unroll
            for (int r = 0; r < 4; ++r) {
                float v = acc1[t][r];
                v = v > 0.f ? v : 0.f;
                h_s[wave][g * 4 + r][t * 16 + m] = f2bf(v);
            }
        }
        lds_fence();

        // ---------------- layer 2: h1(16x64) @ W2(64x64) ------------------
        bf16x8 a2[2];
        #pragma unroll
        for (int kk = 0; kk < 2; ++kk) {
            ushortx8 u = *reinterpret_cast<const ushortx8*>(&h_s[wave][m][kk * 32 + kb]);
            a2[kk] = __builtin_bit_cast(bf16x8, u);
        }
        floatx4 acc2[4];
        #pragma unroll
        for (int t = 0; t < 4; ++t) {
            float b = bias2[t];
            acc2[t] = (floatx4){b, b, b, b};
        }
        #pragma unroll
        for (int kk = 0; kk < 2; ++kk) {
            #pragma unroll
            for (int t = 0; t < 4; ++t) {
                acc2[t] = __builtin_amdgcn_mfma_f32_16x16x32_bf16(a2[kk], B2h[kk][t], acc2[t], 0, 0, 0);
                acc2[t] = __builtin_amdgcn_mfma_f32_16x16x32_bf16(a2[kk], B2l[kk][t], acc2[t], 0, 0, 0);
            }
        }

        // relu -> LDS (WAR on h_s is same-wave in-order + fence-separated)
        #pragma unroll
        for (int t = 0; t < 4; ++t) {
            #pragma unroll
            for (int r = 0; r < 4; ++r) {
                float v = acc2[t][r];
                v = v > 0.f ? v : 0.f;
                h_s[wave][g * 4 + r][t * 16 + m] = f2bf(v);
            }
        }
        lds_fence();

        // ---------------- layer 3: h2(16x64) @ W3(64x16 padded) -----------
        bf16x8 a3[2];
        #pragma unroll
        for (int kk = 0; kk < 2; ++kk) {
            ushortx8 u = *reinterpret_cast<const ushortx8*>(&h_s[wave][m][kk * 32 + kb]);
            a3[kk] = __builtin_bit_cast(bf16x8, u);
        }
        floatx4 acc3 = (floatx4){bias3, bias3, bias3, bias3};
        #pragma unroll
        for (int kk = 0; kk < 2; ++kk) {
            acc3 = __builtin_amdgcn_mfma_f32_16x16x32_bf16(a3[kk], B3h[kk], acc3, 0, 0, 0);
            acc3 = __builtin_amdgcn_mfma_f32_16x16x32_bf16(a3[kk], B3l[kk], acc3, 0, 0, 0);
        }

        // direct stores: lane (g,m) m<4 holds out[pbase+g*4+r][m], r=0..3
        if (m < 4) {
            #pragma unroll
            for (int r = 0; r < 4; ++r)
                out[(long)(pbase + g * 4 + r) * 4 + m] = acc3[r];
        }
    }
}

extern "C" void kernel_launch(void* const* d_in, const int* in_sizes, int n_in,
                              void* d_out, int out_size, void* d_ws, size_t ws_size,
                              hipStream_t stream) {
    const float* coords = (const float*)d_in[0];
    const float* W1 = (const float*)d_in[1];
    const float* b1 = (const float*)d_in[2];
    const float* W2 = (const float*)d_in[3];
    const float* b2 = (const float*)d_in[4];
    const float* W3 = (const float*)d_in[5];
    const float* b3 = (const float*)d_in[6];
    float* outp = (float*)d_out;

    const int npts = in_sizes[0] / 3;           // 2,097,152
    const int nblocks = 2048;                   // 8192 waves; 131072 % 8192 == 0
    hipLaunchKernelGGL(nerf_fused_kernel, dim3(nblocks), dim3(256), 0, stream,
                       coords, W1, b1, W2, b2, W3, b3, outp, npts);
}

// Round 6
// 111.104 us; speedup vs baseline: 1.2133x; 1.1510x over previous
//
#include <hip/hip_runtime.h>

typedef unsigned short ushort_t;
typedef __bf16   bf16x8  __attribute__((ext_vector_type(8)));
typedef float    floatx4 __attribute__((ext_vector_type(4)));
typedef ushort_t ushortx8 __attribute__((ext_vector_type(8)));

__device__ __forceinline__ float bf2f(ushort_t u) {
    unsigned int x = ((unsigned int)u) << 16;
    return __builtin_bit_cast(float, x);
}
__device__ __forceinline__ ushort_t f2bf(float f) {
    unsigned int x = __builtin_bit_cast(unsigned int, f);
    x += 0x7fffu + ((x >> 16) & 1u);   // RNE
    return (ushort_t)(x >> 16);
}
__device__ __forceinline__ __bf16 f2bf16t(float f) {
    ushort_t u = f2bf(f);
    return __builtin_bit_cast(__bf16, u);
}
// same-wave LDS write->read fence (rule #18: asm waitcnt + sched_barrier)
__device__ __forceinline__ void lds_fence() {
    asm volatile("s_waitcnt lgkmcnt(0)" ::: "memory");
    __builtin_amdgcn_sched_barrier(0);
}

#define INV2PI 0.15915494309189535f

// N3R fused PE + 3-layer MLP.  Inputs f32 (harness upcasts f16), output f32.
// One wave = 16 points/iter via mfma_f32_16x16x32_bf16; hi/lo-split weights.
// PE via native v_sin_f32 in revolution space (cos = sin(+0.25 rev)).
__global__ __launch_bounds__(256) void nerf_fused_kernel(
    const float* __restrict__ coords,
    const float* __restrict__ W1, const float* __restrict__ b1,
    const float* __restrict__ W2, const float* __restrict__ b2,
    const float* __restrict__ W3, const float* __restrict__ b3,
    float* __restrict__ out, int npts)
{
    // per-wave [16 rows][64+8 pad cols] bf16 tile (2304 B each, 9216 B/block)
    __shared__ __align__(16) ushort_t h_s[4][16][72];

    const int tid  = threadIdx.x;
    const int wave = tid >> 6;
    const int lane = tid & 63;
    const int m    = lane & 15;       // MFMA row (A) / col (B,D)
    const int g    = lane >> 4;       // quarter-wave group
    const int kb   = g * 8;           // this lane's K-base within a K=32 chunk

    // ---------------- weight fragments (hi/lo split, in registers) --------
    // B-frag layout: lane holds B[k = kb+i][n = t*16 + (lane&15)]
    bf16x8 B1h[4], B1l[4];
    #pragma unroll
    for (int t = 0; t < 4; ++t) {
        #pragma unroll
        for (int i = 0; i < 8; ++i) {
            int k = kb + i;
            int n = t * 16 + m;
            float w = (k < 27) ? W1[k * 64 + n] : 0.f;
            ushort_t hi = f2bf(w);
            B1h[t][i] = __builtin_bit_cast(__bf16, hi);
            B1l[t][i] = f2bf16t(w - bf2f(hi));
        }
    }
    bf16x8 B2h[2][4], B2l[2][4];   // [k-chunk][n-tile]
    #pragma unroll
    for (int kk = 0; kk < 2; ++kk) {
        #pragma unroll
        for (int t = 0; t < 4; ++t) {
            #pragma unroll
            for (int i = 0; i < 8; ++i) {
                int k = kk * 32 + kb + i;
                int n = t * 16 + m;
                float w = W2[k * 64 + n];
                ushort_t hi = f2bf(w);
                B2h[kk][t][i] = __builtin_bit_cast(__bf16, hi);
                B2l[kk][t][i] = f2bf16t(w - bf2f(hi));
            }
        }
    }
    bf16x8 B3h[2], B3l[2];         // N padded 4 -> 16 with zeros
    #pragma unroll
    for (int kk = 0; kk < 2; ++kk) {
        #pragma unroll
        for (int i = 0; i < 8; ++i) {
            int k = kk * 32 + kb + i;
            float w = (m < 4) ? W3[k * 4 + m] : 0.f;
            ushort_t hi = f2bf(w);
            B3h[kk][i] = __builtin_bit_cast(__bf16, hi);
            B3l[kk][i] = f2bf16t(w - bf2f(hi));
        }
    }
    float bias1[4], bias2[4];
    #pragma unroll
    for (int t = 0; t < 4; ++t) {
        bias1[t] = b1[t * 16 + m];
        bias2[t] = b2[t * 16 + m];
    }
    const float bias3 = (m < 4) ? b3[m] : 0.f;

    // ---- per-lane PE feature descriptors (hoisted out of the hot loop) ----
    // feature j = kb+i.  j<3: identity coord j.  3<=j<27: mm=j-3, l=mm/6,
    // rem=mm%6, cosflag=rem>=3, c=rem%3 -> sin(2pi*(x_c*2^l*INV2PI + .25*cf)).
    // j>=27: scale=bias=0 -> sin(0)=0 exact pad.
    float fscale[8], fbias[8];
    int   fc[8];      // coord selector 0/1/2
    int   fident[8];  // identity feature (g==0, i<3)
    #pragma unroll
    for (int i = 0; i < 8; ++i) {
        int j = kb + i;
        if (j < 3) {
            fc[i] = j; fident[i] = 1; fscale[i] = 0.f; fbias[i] = 0.f;
        } else if (j < 27) {
            int mm  = j - 3;
            int lv  = mm / 6;
            int rem = mm - lv * 6;
            int sfl = (rem >= 3);
            fc[i]     = rem - (sfl ? 3 : 0);
            fident[i] = 0;
            fscale[i] = (float)(1 << lv) * INV2PI;
            fbias[i]  = sfl ? 0.25f : 0.f;
        } else {
            fc[i] = 0; fident[i] = 0; fscale[i] = 0.f; fbias[i] = 0.f;
        }
    }

    // ---------------- main loop: 16 points per wave-iteration -------------
    const int nt16 = npts >> 4;
    const int gw   = blockIdx.x * 4 + wave;
    const int nw   = gridDim.x * 4;

    // prefetch first tile's coords
    float nx0 = 0.f, nx1 = 0.f, nx2 = 0.f;
    if (gw < nt16) {
        long cb = (long)((gw << 4) + m) * 3;
        nx0 = coords[cb + 0]; nx1 = coords[cb + 1]; nx2 = coords[cb + 2];
    }

    for (int t16 = gw; t16 < nt16; t16 += nw) {
        const int pbase = t16 << 4;
        const float x0 = nx0, x1 = nx1, x2 = nx2;

        // issue next tile's coord loads now; latency hides under compute
        {
            int nt = t16 + nw; if (nt >= nt16) nt = t16;   // clamped, unused
            long cb = (long)((nt << 4) + m) * 3;
            nx0 = coords[cb + 0]; nx1 = coords[cb + 1]; nx2 = coords[cb + 2];
        }

        // ---- positional encoding: this lane's 8 enc features kb..kb+7 ----
        bf16x8 a1;
        #pragma unroll
        for (int i = 0; i < 8; ++i) {
            float xv = (fc[i] == 2) ? x2 : ((fc[i] == 1) ? x1 : x0);
            float sv = __builtin_amdgcn_sinf(fmaf(xv, fscale[i], fbias[i]));
            float v  = fident[i] ? xv : sv;
            a1[i] = f2bf16t(v);
        }

        // ---------------- layer 1: enc(16x32) @ W1(32x64) ----------------
        floatx4 acc1[4];
        #pragma unroll
        for (int t = 0; t < 4; ++t) {
            float b = bias1[t];
            acc1[t] = (floatx4){b, b, b, b};     // bias folded into acc init
        }
        #pragma unroll
        for (int t = 0; t < 4; ++t) {
            acc1[t] = __builtin_amdgcn_mfma_f32_16x16x32_bf16(a1, B1h[t], acc1[t], 0, 0, 0);
            acc1[t] = __builtin_amdgcn_mfma_f32_16x16x32_bf16(a1, B1l[t], acc1[t], 0, 0, 0);
        }

        // relu -> LDS rows (D layout: row = g*4+r, col = t*16+m)
        #pragma unroll
        for (int t = 0; t < 4; ++t) {
            #pragma unroll
            for (int r = 0; r < 4; ++r) {
                float v = acc1[t][r];
                v = v > 0.f ? v : 0.f;
                h_s[wave][g * 4 + r][t * 16 + m] = f2bf(v);
            }
        }
        lds_fence();

        // ---------------- layer 2: h1(16x64) @ W2(64x64) ------------------
        bf16x8 a2[2];
        #pragma unroll
        for (int kk = 0; kk < 2; ++kk) {
            ushortx8 u = *reinterpret_cast<const ushortx8*>(&h_s[wave][m][kk * 32 + kb]);
            a2[kk] = __builtin_bit_cast(bf16x8, u);
        }
        floatx4 acc2[4];
        #pragma unroll
        for (int t = 0; t < 4; ++t) {
            float b = bias2[t];
            acc2[t] = (floatx4){b, b, b, b};
        }
        #pragma unroll
        for (int kk = 0; kk < 2; ++kk) {
            #pragma unroll
            for (int t = 0; t < 4; ++t) {
                acc2[t] = __builtin_amdgcn_mfma_f32_16x16x32_bf16(a2[kk], B2h[kk][t], acc2[t], 0, 0, 0);
                acc2[t] = __builtin_amdgcn_mfma_f32_16x16x32_bf16(a2[kk], B2l[kk][t], acc2[t], 0, 0, 0);
            }
        }

        // relu -> LDS (WAR on h_s is same-wave in-order + fence-separated)
        #pragma unroll
        for (int t = 0; t < 4; ++t) {
            #pragma unroll
            for (int r = 0; r < 4; ++r) {
                float v = acc2[t][r];
                v = v > 0.f ? v : 0.f;
                h_s[wave][g * 4 + r][t * 16 + m] = f2bf(v);
            }
        }
        lds_fence();

        // ---------------- layer 3: h2(16x64) @ W3(64x16 padded) -----------
        bf16x8 a3[2];
        #pragma unroll
        for (int kk = 0; kk < 2; ++kk) {
            ushortx8 u = *reinterpret_cast<const ushortx8*>(&h_s[wave][m][kk * 32 + kb]);
            a3[kk] = __builtin_bit_cast(bf16x8, u);
        }
        floatx4 acc3 = (floatx4){bias3, bias3, bias3, bias3};
        #pragma unroll
        for (int kk = 0; kk < 2; ++kk) {
            acc3 = __builtin_amdgcn_mfma_f32_16x16x32_bf16(a3[kk], B3h[kk], acc3, 0, 0, 0);
            acc3 = __builtin_amdgcn_mfma_f32_16x16x32_bf16(a3[kk], B3l[kk], acc3, 0, 0, 0);
        }

        // direct stores: lane (g,m) m<4 holds out[pbase+g*4+r][m], r=0..3
        if (m < 4) {
            #pragma unroll
            for (int r = 0; r < 4; ++r)
                out[(long)(pbase + g * 4 + r) * 4 + m] = acc3[r];
        }
    }
}

extern "C" void kernel_launch(void* const* d_in, const int* in_sizes, int n_in,
                              void* d_out, int out_size, void* d_ws, size_t ws_size,
                              hipStream_t stream) {
    const float* coords = (const float*)d_in[0];
    const float* W1 = (const float*)d_in[1];
    const float* b1 = (const float*)d_in[2];
    const float* W2 = (const float*)d_in[3];
    const float* b2 = (const float*)d_in[4];
    const float* W3 = (const float*)d_in[5];
    const float* b3 = (const float*)d_in[6];
    float* outp = (float*)d_out;

    const int npts = in_sizes[0] / 3;           // 2,097,152
    const int nblocks = 2048;                   // 8192 waves; 131072 % 8192 == 0
    hipLaunchKernelGGL(nerf_fused_kernel, dim3(nblocks), dim3(256), 0, stream,
                       coords, W1, b1, W2, b2, W3, b3, outp, npts);
}

// Round 7
// 60.115 us; speedup vs baseline: 2.2424x; 1.8482x over previous
//
#include <hip/hip_runtime.h>

typedef unsigned short ushort_t;
typedef _Float16 f16x8 __attribute__((ext_vector_type(8)));
typedef _Float16 f16x4 __attribute__((ext_vector_type(4)));
typedef float    floatx4 __attribute__((ext_vector_type(4)));

// same-wave LDS write->read fence (rule #18: asm waitcnt + sched_barrier)
__device__ __forceinline__ void lds_fence() {
    asm volatile("s_waitcnt lgkmcnt(0)" ::: "memory");
    __builtin_amdgcn_sched_barrier(0);
}

#define INV2PI 0.15915494309189535f

// N3R fused PE + 3-layer MLP.  Inputs f32 (harness upcast of f16 tensors),
// output f32.  One wave = 16 points/iter via mfma_f32_16x16x32_f16 with
// EXACT f16 weights (no hi/lo split needed).
//
// K-row permutations (all free, applied at weight-load time):
//  - Layer 1: slot (g,i): i<6 -> enc feature 3+6g+3*(i>=3)+(i%3)
//             (lane group g owns frequency 2^g; i<3 sin, 3<=i<6 cos);
//             (0,6)=x0 (0,7)=x1 (1,6)=x2 (1,7)=bias row (a==1); rest pad.
//  - h1/h2 LDS layout: logical feature c=16t+m stored at physical col 4m+t
//    so each lane's 4 outputs per r pack into one ds_write_b64; B2/B3 use
//    k_logical(j) = 16*(j&3) + (j>>2).
__global__ __launch_bounds__(256, 4) void nerf_fused_kernel(
    const float* __restrict__ coords,
    const float* __restrict__ W1, const float* __restrict__ b1,
    const float* __restrict__ W2, const float* __restrict__ b2,
    const float* __restrict__ W3, const float* __restrict__ b3,
    float* __restrict__ out, int npts)
{
    // per-wave [16 rows][64+8 pad cols] f16 tile
    __shared__ __align__(16) _Float16 h_s[4][16][72];

    const int tid  = threadIdx.x;
    const int wave = tid >> 6;
    const int lane = tid & 63;
    const int m    = lane & 15;       // MFMA row (A) / col (B,D)
    const int g    = lane >> 4;       // quarter-wave group
    const int kb   = g * 8;           // K-base within a K=32 chunk

    // ---------------- weight fragments (f16, exact) -----------------------
    f16x8 B1f[4];
    #pragma unroll
    for (int t = 0; t < 4; ++t) {
        int n = t * 16 + m;
        #pragma unroll
        for (int i = 0; i < 8; ++i) {
            float w;
            if (i < 6) {
                w = W1[(3 + 6 * g + 3 * (i >= 3 ? 1 : 0) + (i % 3)) * 64 + n];
            } else {
                int j = kb + i;            // global slot id
                if      (j == 6)  w = W1[0 * 64 + n];
                else if (j == 7)  w = W1[1 * 64 + n];
                else if (j == 14) w = W1[2 * 64 + n];
                else if (j == 15) w = b1[n];          // bias row (a==1)
                else              w = 0.f;            // pad
            }
            B1f[t][i] = (_Float16)w;
        }
    }
    f16x8 B2f[2][4];   // [k-chunk][n-tile], k-permuted
    #pragma unroll
    for (int kk = 0; kk < 2; ++kk) {
        #pragma unroll
        for (int t = 0; t < 4; ++t) {
            int n = t * 16 + m;
            #pragma unroll
            for (int i = 0; i < 8; ++i) {
                int j = kk * 32 + kb + i;
                int kl = 16 * (j & 3) + (j >> 2);
                B2f[kk][t][i] = (_Float16)W2[kl * 64 + n];
            }
        }
    }
    f16x8 B3f[2];      // N padded 4 -> 16 with zeros, k-permuted
    #pragma unroll
    for (int kk = 0; kk < 2; ++kk) {
        #pragma unroll
        for (int i = 0; i < 8; ++i) {
            int j = kk * 32 + kb + i;
            int kl = 16 * (j & 3) + (j >> 2);
            B3f[kk][i] = (_Float16)((m < 4) ? W3[kl * 4 + m] : 0.f);
        }
    }
    float bias2[4];
    #pragma unroll
    for (int t = 0; t < 4; ++t) bias2[t] = b2[t * 16 + m];
    const float bias3 = (m < 4) ? b3[m] : 0.f;

    const float sg = __builtin_amdgcn_ldexpf(INV2PI, g);  // 2^g / (2*pi)

    // ---------------- main loop: 16 points per wave-iteration -------------
    const int nt16 = npts >> 4;
    const int gw   = blockIdx.x * 4 + wave;
    const int nw   = gridDim.x * 4;

    for (int t16 = gw; t16 < nt16; t16 += nw) {
        const int pbase = t16 << 4;

        const long cbase = (long)(pbase + m) * 3;
        const float x0 = coords[cbase + 0];
        const float x1 = coords[cbase + 1];
        const float x2 = coords[cbase + 2];

        // ---- PE: lane's 8 enc slots (uniform trig + 2 special slots) -----
        f16x8 a1;
        #pragma unroll
        for (int i = 0; i < 6; ++i) {
            float xv = (i % 3 == 0) ? x0 : ((i % 3 == 1) ? x1 : x2);
            float ph = (i >= 3) ? 0.25f : 0.f;
            a1[i] = (_Float16)__builtin_amdgcn_sinf(fmaf(xv, sg, ph));
        }
        {
            float v6 = (g == 0) ? x0 : ((g == 1) ? x2 : 0.f);
            float v7 = (g == 0) ? x1 : ((g == 1) ? 1.f : 0.f);  // 1 -> bias row
            a1[6] = (_Float16)v6;
            a1[7] = (_Float16)v7;
        }

        // ---------------- layer 1: enc(16x32) @ W1(32x64) ----------------
        floatx4 acc1[4];
        #pragma unroll
        for (int t = 0; t < 4; ++t) acc1[t] = (floatx4){0.f, 0.f, 0.f, 0.f};
        #pragma unroll
        for (int t = 0; t < 4; ++t)
            acc1[t] = __builtin_amdgcn_mfma_f32_16x16x32_f16(a1, B1f[t], acc1[t], 0, 0, 0);

        // relu -> permuted LDS: feature 16t+m at physical col 4m+t
        #pragma unroll
        for (int r = 0; r < 4; ++r) {
            f16x4 pk;
            #pragma unroll
            for (int t = 0; t < 4; ++t) {
                float v = acc1[t][r];
                pk[t] = (_Float16)(v > 0.f ? v : 0.f);
            }
            *reinterpret_cast<f16x4*>(&h_s[wave][g * 4 + r][4 * m]) = pk;
        }
        lds_fence();

        // ---------------- layer 2: h1(16x64) @ W2(64x64) ------------------
        f16x8 a2[2];
        #pragma unroll
        for (int kk = 0; kk < 2; ++kk)
            a2[kk] = *reinterpret_cast<const f16x8*>(&h_s[wave][m][kk * 32 + kb]);
        floatx4 acc2[4];
        #pragma unroll
        for (int t = 0; t < 4; ++t) {
            float b = bias2[t];
            acc2[t] = (floatx4){b, b, b, b};
        }
        #pragma unroll
        for (int kk = 0; kk < 2; ++kk)
            #pragma unroll
            for (int t = 0; t < 4; ++t)
                acc2[t] = __builtin_amdgcn_mfma_f32_16x16x32_f16(a2[kk], B2f[kk][t], acc2[t], 0, 0, 0);

        // relu -> permuted LDS (same-wave WAR ordered by in-order DS + fence)
        #pragma unroll
        for (int r = 0; r < 4; ++r) {
            f16x4 pk;
            #pragma unroll
            for (int t = 0; t < 4; ++t) {
                float v = acc2[t][r];
                pk[t] = (_Float16)(v > 0.f ? v : 0.f);
            }
            *reinterpret_cast<f16x4*>(&h_s[wave][g * 4 + r][4 * m]) = pk;
        }
        lds_fence();

        // ---------------- layer 3: h2(16x64) @ W3(64x16 padded) -----------
        f16x8 a3[2];
        #pragma unroll
        for (int kk = 0; kk < 2; ++kk)
            a3[kk] = *reinterpret_cast<const f16x8*>(&h_s[wave][m][kk * 32 + kb]);
        floatx4 acc3 = (floatx4){bias3, bias3, bias3, bias3};
        #pragma unroll
        for (int kk = 0; kk < 2; ++kk)
            acc3 = __builtin_amdgcn_mfma_f32_16x16x32_f16(a3[kk], B3f[kk], acc3, 0, 0, 0);

        // direct stores: lane (g,m) m<4 holds out[pbase+g*4+r][m], r=0..3
        if (m < 4) {
            #pragma unroll
            for (int r = 0; r < 4; ++r)
                out[(long)(pbase + g * 4 + r) * 4 + m] = acc3[r];
        }
    }
}

extern "C" void kernel_launch(void* const* d_in, const int* in_sizes, int n_in,
                              void* d_out, int out_size, void* d_ws, size_t ws_size,
                              hipStream_t stream) {
    const float* coords = (const float*)d_in[0];
    const float* W1 = (const float*)d_in[1];
    const float* b1 = (const float*)d_in[2];
    const float* W2 = (const float*)d_in[3];
    const float* b2 = (const float*)d_in[4];
    const float* W3 = (const float*)d_in[5];
    const float* b3 = (const float*)d_in[6];
    float* outp = (float*)d_out;

    const int npts = in_sizes[0] / 3;           // 2,097,152
    const int nblocks = 2048;                   // 8192 waves; 131072 % 8192 == 0
    hipLaunchKernelGGL(nerf_fused_kernel, dim3(nblocks), dim3(256), 0, stream,
                       coords, W1, b1, W2, b2, W3, b3, outp, npts);
}

// Round 8
// 57.613 us; speedup vs baseline: 2.3398x; 1.0434x over previous
//
#include <hip/hip_runtime.h>

typedef _Float16 f16x8 __attribute__((ext_vector_type(8)));
typedef float    floatx4 __attribute__((ext_vector_type(4)));

#define INV2PI 0.15915494309189535f

// N3R fused PE + 3-layer MLP, fully in-register (no LDS, no barriers).
// Inputs f32 (harness upcast of the f16 ref tensors), output f32.
// One wave = 16 points/iter.  All layers computed TRANSPOSED:
//   D^T = W^T(A-operand) @ act^T(B-operand)  via mfma_f32_16x16x32_f16.
// The MFMA D layout (col=point on lane&15, row=feature on (g,reg)) IS the
// next layer's B-fragment layout under a K-row permutation of the next
// weight matrix (applied free at weight-load time):
//   slot k of a K=32 chunk kk  <->  logical feature F(kk,k) =
//       ((k&7)>>2 + 2*kk)*16 + (k>>3)*4 + (k&3)
// so inter-layer "transpose" = static register repack of the accumulator.
// Layer-1 K-permutation: slot (g,i): i<6 -> enc feature 3+6g+3*(i>=3)+(i%3)
// (lane group g owns frequency 2^g; i<3 sin, else cos); slots (0,6)=x0,
// (0,7)=x1, (1,6)=x2, (1,7)=bias row (enc==1); rest zero-pad.
__global__ __launch_bounds__(256, 4) void nerf_fused_kernel(
    const float* __restrict__ coords,
    const float* __restrict__ W1, const float* __restrict__ b1,
    const float* __restrict__ W2, const float* __restrict__ b2,
    const float* __restrict__ W3, const float* __restrict__ b3,
    float* __restrict__ out, int npts)
{
    const int tid  = threadIdx.x;
    const int wave = tid >> 6;
    const int lane = tid & 63;
    const int m    = lane & 15;       // A row (=output feature) / B,D col (=point)
    const int g    = lane >> 4;       // quarter-wave group
    const int kb   = g * 8;           // K-slot base within a K=32 chunk

    // ---------------- A-side weight fragments (f16 exact, transposed) -----
    // A1[t1][i] = W1[encfeat(g,i)][t1*16+m]  (row = out-feature t1*16+m)
    f16x8 A1[4];
    #pragma unroll
    for (int t1 = 0; t1 < 4; ++t1) {
        int n = t1 * 16 + m;
        #pragma unroll
        for (int i = 0; i < 8; ++i) {
            float w;
            if (i < 6) {
                w = W1[(3 + 6 * g + (i >= 3 ? 3 : 0) + (i % 3)) * 64 + n];
            } else if (g == 0) {
                w = (i == 6) ? W1[0 * 64 + n] : W1[1 * 64 + n];
            } else if (g == 1) {
                w = (i == 6) ? W1[2 * 64 + n] : b1[n];   // slot15: bias row
            } else {
                w = 0.f;
            }
            A1[t1][i] = (_Float16)w;
        }
    }
    // A2[t2][kk][i] = W2[F(kk, g*8+i)][t2*16+m]
    f16x8 A2[4][2];
    #pragma unroll
    for (int t2 = 0; t2 < 4; ++t2) {
        int n = t2 * 16 + m;
        #pragma unroll
        for (int kk = 0; kk < 2; ++kk) {
            #pragma unroll
            for (int i = 0; i < 8; ++i) {
                int f = ((i >> 2) + 2 * kk) * 16 + g * 4 + (i & 3);
                A2[t2][kk][i] = (_Float16)W2[f * 64 + n];
            }
        }
    }
    // A3[kk][i] = (m<4) ? W3[F(kk, g*8+i)][m] : 0   (rows 4..15 zero-pad)
    f16x8 A3[2];
    #pragma unroll
    for (int kk = 0; kk < 2; ++kk) {
        #pragma unroll
        for (int i = 0; i < 8; ++i) {
            int f = ((i >> 2) + 2 * kk) * 16 + g * 4 + (i & 3);
            A3[kk][i] = (_Float16)((m < 4) ? W3[f * 4 + m] : 0.f);
        }
    }
    // biases folded into accumulator init (row = g*4+r on this lane)
    float bias2v[4][4];               // [t2][r] = b2[t2*16 + g*4 + r]
    #pragma unroll
    for (int t2 = 0; t2 < 4; ++t2)
        #pragma unroll
        for (int r = 0; r < 4; ++r)
            bias2v[t2][r] = b2[t2 * 16 + g * 4 + r];
    float bias3v[4];                  // row n3 = g*4+r valid only for g==0
    #pragma unroll
    for (int r = 0; r < 4; ++r)
        bias3v[r] = (g == 0) ? b3[r] : 0.f;

    const float sg = __builtin_amdgcn_ldexpf(INV2PI, g);  // 2^g / (2*pi)

    // ---------------- main loop: 16 points per wave-iteration -------------
    const int nt16 = npts >> 4;
    const int gw   = blockIdx.x * 4 + wave;
    const int nw   = gridDim.x * 4;

    for (int t16 = gw; t16 < nt16; t16 += nw) {
        const int pbase = t16 << 4;

        const long cbase = (long)(pbase + m) * 3;
        const float x0 = coords[cbase + 0];
        const float x1 = coords[cbase + 1];
        const float x2 = coords[cbase + 2];

        // ---- B1 = enc^T fragment (col=point m, slots k=g*8+i) ------------
        f16x8 B1;
        #pragma unroll
        for (int i = 0; i < 6; ++i) {
            float xv = (i % 3 == 0) ? x0 : ((i % 3 == 1) ? x1 : x2);
            float ph = (i >= 3) ? 0.25f : 0.f;
            B1[i] = (_Float16)__builtin_amdgcn_sinf(fmaf(xv, sg, ph));
        }
        B1[6] = (_Float16)((g == 0) ? x0 : ((g == 1) ? x2 : 0.f));
        B1[7] = (_Float16)((g == 0) ? x1 : ((g == 1) ? 1.f : 0.f));

        // ---- layer 1: D1^T(64feat x 16pts) = W1^T @ enc^T ----------------
        floatx4 acc1[4];
        #pragma unroll
        for (int t1 = 0; t1 < 4; ++t1) {
            acc1[t1] = (floatx4){0.f, 0.f, 0.f, 0.f};
            acc1[t1] = __builtin_amdgcn_mfma_f32_16x16x32_f16(A1[t1], B1, acc1[t1], 0, 0, 0);
        }

        // ---- repack: relu(D1) -> B2 (static register shuffle) ------------
        // B2[kk] slot i holds h1 feature F(kk,g*8+i) = acc1[(i>>2)+2kk][i&3]
        f16x8 B2[2];
        #pragma unroll
        for (int kk = 0; kk < 2; ++kk)
            #pragma unroll
            for (int i = 0; i < 8; ++i)
                B2[kk][i] = (_Float16)fmaxf(acc1[(i >> 2) + 2 * kk][i & 3], 0.f);

        // ---- layer 2: D2^T(64 x 16) = W2^T @ h1^T ------------------------
        floatx4 acc2[4];
        #pragma unroll
        for (int t2 = 0; t2 < 4; ++t2) {
            acc2[t2] = (floatx4){bias2v[t2][0], bias2v[t2][1],
                                 bias2v[t2][2], bias2v[t2][3]};
            #pragma unroll
            for (int kk = 0; kk < 2; ++kk)
                acc2[t2] = __builtin_amdgcn_mfma_f32_16x16x32_f16(A2[t2][kk], B2[kk], acc2[t2], 0, 0, 0);
        }

        // ---- repack: relu(D2) -> B3 --------------------------------------
        f16x8 B3[2];
        #pragma unroll
        for (int kk = 0; kk < 2; ++kk)
            #pragma unroll
            for (int i = 0; i < 8; ++i)
                B3[kk][i] = (_Float16)fmaxf(acc2[(i >> 2) + 2 * kk][i & 3], 0.f);

        // ---- layer 3: D3^T(16pad x 16) = W3^T @ h2^T ---------------------
        floatx4 acc3 = (floatx4){bias3v[0], bias3v[1], bias3v[2], bias3v[3]};
        #pragma unroll
        for (int kk = 0; kk < 2; ++kk)
            acc3 = __builtin_amdgcn_mfma_f32_16x16x32_f16(A3[kk], B3[kk], acc3, 0, 0, 0);

        // ---- store: lane (g==0, m) holds point pbase+m, channels r=0..3 --
        if (g == 0)
            *reinterpret_cast<floatx4*>(&out[(long)(pbase + m) * 4]) = acc3;
    }
}

extern "C" void kernel_launch(void* const* d_in, const int* in_sizes, int n_in,
                              void* d_out, int out_size, void* d_ws, size_t ws_size,
                              hipStream_t stream) {
    const float* coords = (const float*)d_in[0];
    const float* W1 = (const float*)d_in[1];
    const float* b1 = (const float*)d_in[2];
    const float* W2 = (const float*)d_in[3];
    const float* b2 = (const float*)d_in[4];
    const float* W3 = (const float*)d_in[5];
    const float* b3 = (const float*)d_in[6];
    float* outp = (float*)d_out;

    const int npts = in_sizes[0] / 3;           // 2,097,152
    const int nblocks = 2048;                   // 8192 waves; 131072 % 8192 == 0
    hipLaunchKernelGGL(nerf_fused_kernel, dim3(nblocks), dim3(256), 0, stream,
                       coords, W1, b1, W2, b2, W3, b3, outp, npts);
}

// Round 10
// 47.696 us; speedup vs baseline: 2.8263x; 1.2079x over previous
//
#include <hip/hip_runtime.h>

typedef _Float16 f16x2 __attribute__((ext_vector_type(2)));
typedef _Float16 f16x4_t __attribute__((ext_vector_type(4)));
typedef _Float16 f16x8 __attribute__((ext_vector_type(8)));
typedef float    floatx4 __attribute__((ext_vector_type(4)));

#define INV2PI 0.15915494309189535f

// __builtin_amdgcn_cvt_pkrtz returns __fp16-based vector; bit_cast to our
// _Float16-based f16x2 (identical layout).
__device__ __forceinline__ f16x2 cvt_pk(float a, float b) {
    return __builtin_bit_cast(f16x2, __builtin_amdgcn_cvt_pkrtz(a, b));
}
__device__ __forceinline__ f16x8 pack8(f16x2 a, f16x2 b, f16x2 c, f16x2 d) {
    f16x4_t lo = __builtin_shufflevector(a, b, 0, 1, 2, 3);
    f16x4_t hi = __builtin_shufflevector(c, d, 0, 1, 2, 3);
    return __builtin_shufflevector(lo, hi, 0, 1, 2, 3, 4, 5, 6, 7);
}
__device__ __forceinline__ f16x2 pk_relu(float a, float b) {
    f16x2 h = cvt_pk(a, b);                       // v_cvt_pkrtz_f16_f32
    f16x2 z; z[0] = (_Float16)0.f; z[1] = (_Float16)0.f;
    return __builtin_elementwise_max(h, z);       // v_pk_max_f16
}

// N3R fused PE + 3-layer MLP, fully in-register (no LDS/barriers).
// Inputs f32 (harness upcast of f16 ref tensors), output f32.
// One wave = TWO independent 16-point chains per iteration (shared weight
// regs), transposed layers: D^T = W^T(A) @ act^T(B) via mfma 16x16x32_f16.
// Inter-layer transpose = static register repack (see F(kk,k) permutation,
// applied identically to the next layer's A-side weight load).
__global__ __launch_bounds__(256, 4) void nerf_fused_kernel(
    const float* __restrict__ coords,
    const float* __restrict__ W1, const float* __restrict__ b1,
    const float* __restrict__ W2, const float* __restrict__ b2,
    const float* __restrict__ W3, const float* __restrict__ b3,
    float* __restrict__ out, int npts)
{
    const int tid  = threadIdx.x;
    const int wave = tid >> 6;
    const int lane = tid & 63;
    const int m    = lane & 15;       // A row (out-feature) / B,D col (point)
    const int g    = lane >> 4;       // quarter-wave group (owns freq 2^g)

    // ---------------- A-side weight fragments (f16 exact, transposed) -----
    // Layer-1 K-slot (g,i): i<6 -> enc feature 3+6g+3*(i>=3)+(i%3);
    // (0,6)=x0 (0,7)=x1 (1,6)=x2 (1,7)=bias row (enc==1); rest zero-pad.
    f16x8 A1[4];
    #pragma unroll
    for (int t1 = 0; t1 < 4; ++t1) {
        int n = t1 * 16 + m;
        #pragma unroll
        for (int i = 0; i < 8; ++i) {
            float w;
            if (i < 6)        w = W1[(3 + 6 * g + (i >= 3 ? 3 : 0) + (i % 3)) * 64 + n];
            else if (g == 0)  w = (i == 6) ? W1[0 * 64 + n] : W1[1 * 64 + n];
            else if (g == 1)  w = (i == 6) ? W1[2 * 64 + n] : b1[n];
            else              w = 0.f;
            A1[t1][i] = (_Float16)w;
        }
    }
    // F(kk, g*8+i) = ((i>>2)+2kk)*16 + g*4 + (i&3)  (D-layout-induced perm)
    f16x8 A2[4][2];
    #pragma unroll
    for (int t2 = 0; t2 < 4; ++t2) {
        int n = t2 * 16 + m;
        #pragma unroll
        for (int kk = 0; kk < 2; ++kk)
            #pragma unroll
            for (int i = 0; i < 8; ++i) {
                int f = ((i >> 2) + 2 * kk) * 16 + g * 4 + (i & 3);
                A2[t2][kk][i] = (_Float16)W2[f * 64 + n];
            }
    }
    f16x8 A3[2];
    #pragma unroll
    for (int kk = 0; kk < 2; ++kk)
        #pragma unroll
        for (int i = 0; i < 8; ++i) {
            int f = ((i >> 2) + 2 * kk) * 16 + g * 4 + (i & 3);
            A3[kk][i] = (_Float16)((m < 4) ? W3[f * 4 + m] : 0.f);
        }

    floatx4 bias2q[4];
    #pragma unroll
    for (int t2 = 0; t2 < 4; ++t2)
        #pragma unroll
        for (int r = 0; r < 4; ++r)
            bias2q[t2][r] = b2[t2 * 16 + g * 4 + r];
    floatx4 bias3q;
    #pragma unroll
    for (int r = 0; r < 4; ++r)
        bias3q[r] = (g == 0) ? b3[r] : 0.f;

    const float sg = __builtin_amdgcn_ldexpf(INV2PI, g);   // 2^g / (2*pi)

    // ---------------- main loop: 32 points (2 chains) per iteration -------
    const int nt32 = npts >> 5;                 // 65536 tiles
    const int gw   = blockIdx.x * 4 + wave;     // 8192 waves -> 8 iters/wave
    const int nw   = gridDim.x * 4;

    float cx[2][3];                             // prefetched coords
    {
        long nb = ((long)(gw << 5) + m) * 3;
        #pragma unroll
        for (int j = 0; j < 3; ++j) { cx[0][j] = coords[nb + j]; cx[1][j] = coords[nb + 48 + j]; }
    }

    for (int t32 = gw; t32 < nt32; t32 += nw) {
        const int pbase = t32 << 5;

        float x[2][3];
        #pragma unroll
        for (int p = 0; p < 2; ++p)
            #pragma unroll
            for (int j = 0; j < 3; ++j) x[p][j] = cx[p][j];

        // issue next tile's loads; latency hides under this iter's compute
        {
            int tn = t32 + nw; if (tn >= nt32) tn = t32;   // clamped reload
            long nb = ((long)(tn << 5) + m) * 3;
            #pragma unroll
            for (int j = 0; j < 3; ++j) { cx[0][j] = coords[nb + j]; cx[1][j] = coords[nb + 48 + j]; }
        }

        // ---- PE -> B1 fragments (packed) ---------------------------------
        f16x8 B1[2];
        #pragma unroll
        for (int p = 0; p < 2; ++p) {
            float s[6];
            #pragma unroll
            for (int i = 0; i < 6; ++i) {
                float xv = x[p][i % 3];
                float ph = (i >= 3) ? 0.25f : 0.f;
                s[i] = __builtin_amdgcn_sinf(fmaf(xv, sg, ph));
            }
            float v6 = (g == 0) ? x[p][0] : ((g == 1) ? x[p][2] : 0.f);
            float v7 = (g == 0) ? x[p][1] : ((g == 1) ? 1.f : 0.f);
            B1[p] = pack8(cvt_pk(s[0], s[1]),
                          cvt_pk(s[2], s[3]),
                          cvt_pk(s[4], s[5]),
                          cvt_pk(v6, v7));
        }

        // ---- layer 1 ------------------------------------------------------
        floatx4 acc1[2][4];
        #pragma unroll
        for (int t1 = 0; t1 < 4; ++t1)
            #pragma unroll
            for (int p = 0; p < 2; ++p) {
                acc1[p][t1] = (floatx4){0.f, 0.f, 0.f, 0.f};
                acc1[p][t1] = __builtin_amdgcn_mfma_f32_16x16x32_f16(A1[t1], B1[p], acc1[p][t1], 0, 0, 0);
            }

        // ---- repack relu(D1) -> B2 (packed static shuffle) ---------------
        f16x8 B2[2][2];
        #pragma unroll
        for (int p = 0; p < 2; ++p)
            #pragma unroll
            for (int kk = 0; kk < 2; ++kk)
                B2[p][kk] = pack8(
                    pk_relu(acc1[p][2 * kk][0],     acc1[p][2 * kk][1]),
                    pk_relu(acc1[p][2 * kk][2],     acc1[p][2 * kk][3]),
                    pk_relu(acc1[p][2 * kk + 1][0], acc1[p][2 * kk + 1][1]),
                    pk_relu(acc1[p][2 * kk + 1][2], acc1[p][2 * kk + 1][3]));

        // ---- layer 2 ------------------------------------------------------
        floatx4 acc2[2][4];
        #pragma unroll
        for (int t2 = 0; t2 < 4; ++t2)
            #pragma unroll
            for (int p = 0; p < 2; ++p) {
                acc2[p][t2] = bias2q[t2];
                #pragma unroll
                for (int kk = 0; kk < 2; ++kk)
                    acc2[p][t2] = __builtin_amdgcn_mfma_f32_16x16x32_f16(A2[t2][kk], B2[p][kk], acc2[p][t2], 0, 0, 0);
            }

        // ---- repack relu(D2) -> B3 ---------------------------------------
        f16x8 B3[2][2];
        #pragma unroll
        for (int p = 0; p < 2; ++p)
            #pragma unroll
            for (int kk = 0; kk < 2; ++kk)
                B3[p][kk] = pack8(
                    pk_relu(acc2[p][2 * kk][0],     acc2[p][2 * kk][1]),
                    pk_relu(acc2[p][2 * kk][2],     acc2[p][2 * kk][3]),
                    pk_relu(acc2[p][2 * kk + 1][0], acc2[p][2 * kk + 1][1]),
                    pk_relu(acc2[p][2 * kk + 1][2], acc2[p][2 * kk + 1][3]));

        // ---- layer 3 + store ---------------------------------------------
        #pragma unroll
        for (int p = 0; p < 2; ++p) {
            floatx4 acc3 = bias3q;
            #pragma unroll
            for (int kk = 0; kk < 2; ++kk)
                acc3 = __builtin_amdgcn_mfma_f32_16x16x32_f16(A3[kk], B3[p][kk], acc3, 0, 0, 0);
            if (g == 0)
                *reinterpret_cast<floatx4*>(&out[(long)(pbase + 16 * p + m) * 4]) = acc3;
        }
    }
}

extern "C" void kernel_launch(void* const* d_in, const int* in_sizes, int n_in,
                              void* d_out, int out_size, void* d_ws, size_t ws_size,
                              hipStream_t stream) {
    const float* coords = (const float*)d_in[0];
    const float* W1 = (const float*)d_in[1];
    const float* b1 = (const float*)d_in[2];
    const float* W2 = (const float*)d_in[3];
    const float* b2 = (const float*)d_in[4];
    const float* W3 = (const float*)d_in[5];
    const float* b3 = (const float*)d_in[6];
    float* outp = (float*)d_out;

    const int npts = in_sizes[0] / 3;           // 2,097,152
    const int nblocks = 2048;                   // 8192 waves; 65536 % 8192 == 0
    hipLaunchKernelGGL(nerf_fused_kernel, dim3(nblocks), dim3(256), 0, stream,
                       coords, W1, b1, W2, b2, W3, b3, outp, npts);
}

// Round 11
// 44.877 us; speedup vs baseline: 3.0038x; 1.0628x over previous
//
#include <hip/hip_runtime.h>

typedef _Float16 f16x2 __attribute__((ext_vector_type(2)));
typedef _Float16 f16x4_t __attribute__((ext_vector_type(4)));
typedef _Float16 f16x8 __attribute__((ext_vector_type(8)));
typedef float    floatx4 __attribute__((ext_vector_type(4)));

#define INV2PI 0.15915494309189535f

__device__ __forceinline__ f16x2 cvt_pk(float a, float b) {
    return __builtin_bit_cast(f16x2, __builtin_amdgcn_cvt_pkrtz(a, b));
}
__device__ __forceinline__ f16x2 pk_relu(f16x2 h) {
    f16x2 z; z[0] = (_Float16)0.f; z[1] = (_Float16)0.f;
    return __builtin_elementwise_max(h, z);       // v_pk_max_f16
}
__device__ __forceinline__ f16x4_t cat2(f16x2 a, f16x2 b) {
    return __builtin_shufflevector(a, b, 0, 1, 2, 3);
}
__device__ __forceinline__ f16x8 cat4(f16x4_t a, f16x4_t b) {
    return __builtin_shufflevector(a, b, 0, 1, 2, 3, 4, 5, 6, 7);
}

// N3R fused PE + 3-layer MLP, fully in-register (no LDS/barriers).
// Inputs f32 (harness upcast of f16 ref tensors), output f32.
// One wave = TWO independent 16-point chains/iter; transposed layers
// D^T = W^T(A) @ act^T(B) via mfma_f32_16x16x32_f16.  Inter-layer
// transpose = static register repack, now FUSED per output-tile t:
// acc of tile t supplies exactly slots 4*(t&1)..+3 of next-B fragment
// t>>1  (F(kk,g*8+i) = ((i>>2)+2kk)*16+g*4+(i&3), so t = (i>>2)+2kk).
// Fusing cuts peak accumulator liveness 64->16 regs -> 4 waves/SIMD.
__global__ __launch_bounds__(256, 4) void nerf_fused_kernel(
    const float* __restrict__ coords,
    const float* __restrict__ W1, const float* __restrict__ b1,
    const float* __restrict__ W2, const float* __restrict__ b2,
    const float* __restrict__ W3, const float* __restrict__ b3,
    float* __restrict__ out, int npts)
{
    const int tid  = threadIdx.x;
    const int wave = tid >> 6;
    const int lane = tid & 63;
    const int m    = lane & 15;       // A row (out-feature) / B,D col (point)
    const int g    = lane >> 4;       // quarter-wave group (owns freq 2^g)

    // ---------------- A-side weight fragments (f16 exact, transposed) -----
    // Layer-1 K-slot (g,i): i<6 -> enc feature 3+6g+3*(i>=3)+(i%3);
    // (0,6)=x0 (0,7)=x1 (1,6)=x2 (1,7)=bias row (enc==1); rest zero-pad.
    f16x8 A1[4];
    #pragma unroll
    for (int t1 = 0; t1 < 4; ++t1) {
        int n = t1 * 16 + m;
        #pragma unroll
        for (int i = 0; i < 8; ++i) {
            float w;
            if (i < 6)        w = W1[(3 + 6 * g + (i >= 3 ? 3 : 0) + (i % 3)) * 64 + n];
            else if (g == 0)  w = (i == 6) ? W1[0 * 64 + n] : W1[1 * 64 + n];
            else if (g == 1)  w = (i == 6) ? W1[2 * 64 + n] : b1[n];
            else              w = 0.f;
            A1[t1][i] = (_Float16)w;
        }
    }
    f16x8 A2[4][2];
    #pragma unroll
    for (int t2 = 0; t2 < 4; ++t2) {
        int n = t2 * 16 + m;
        #pragma unroll
        for (int kk = 0; kk < 2; ++kk)
            #pragma unroll
            for (int i = 0; i < 8; ++i) {
                int f = ((i >> 2) + 2 * kk) * 16 + g * 4 + (i & 3);
                A2[t2][kk][i] = (_Float16)W2[f * 64 + n];
            }
    }
    f16x8 A3[2];
    #pragma unroll
    for (int kk = 0; kk < 2; ++kk)
        #pragma unroll
        for (int i = 0; i < 8; ++i) {
            int f = ((i >> 2) + 2 * kk) * 16 + g * 4 + (i & 3);
            A3[kk][i] = (_Float16)((m < 4) ? W3[f * 4 + m] : 0.f);
        }

    // bias2 packed f16 pairs: b2pk[t2][h] = (b2[t2*16+g*4+2h], ...+2h+1)
    f16x2 b2pk[4][2];
    #pragma unroll
    for (int t2 = 0; t2 < 4; ++t2)
        #pragma unroll
        for (int h = 0; h < 2; ++h)
            b2pk[t2][h] = cvt_pk(b2[t2 * 16 + g * 4 + 2 * h],
                                 b2[t2 * 16 + g * 4 + 2 * h + 1]);
    floatx4 bias3q;
    #pragma unroll
    for (int r = 0; r < 4; ++r)
        bias3q[r] = (g == 0) ? b3[r] : 0.f;

    const float sg = __builtin_amdgcn_ldexpf(INV2PI, g);   // 2^g / (2*pi)

    // ---------------- main loop: 32 points (2 chains) per iteration -------
    const int nt32 = npts >> 5;                 // 65536 tiles
    const int gw   = blockIdx.x * 4 + wave;     // 8192 waves -> 8 iters/wave
    const int nw   = gridDim.x * 4;

    float cx[2][3];                             // prefetched coords
    {
        long nb = ((long)(gw << 5) + m) * 3;
        #pragma unroll
        for (int j = 0; j < 3; ++j) { cx[0][j] = coords[nb + j]; cx[1][j] = coords[nb + 48 + j]; }
    }

    for (int t32 = gw; t32 < nt32; t32 += nw) {
        const int pbase = t32 << 5;

        float x[2][3];
        #pragma unroll
        for (int p = 0; p < 2; ++p)
            #pragma unroll
            for (int j = 0; j < 3; ++j) x[p][j] = cx[p][j];

        // issue next tile's loads; latency hides under this iter's compute
        {
            int tn = t32 + nw; if (tn >= nt32) tn = t32;   // clamped reload
            long nb = ((long)(tn << 5) + m) * 3;
            #pragma unroll
            for (int j = 0; j < 3; ++j) { cx[0][j] = coords[nb + j]; cx[1][j] = coords[nb + 48 + j]; }
        }

        // ---- PE -> B1 fragments (packed) ---------------------------------
        f16x8 B1[2];
        #pragma unroll
        for (int p = 0; p < 2; ++p) {
            float s[6];
            #pragma unroll
            for (int i = 0; i < 6; ++i) {
                float xv = x[p][i % 3];
                float ph = (i >= 3) ? 0.25f : 0.f;
                s[i] = __builtin_amdgcn_sinf(fmaf(xv, sg, ph));
            }
            float v6 = (g == 0) ? x[p][0] : ((g == 1) ? x[p][2] : 0.f);
            float v7 = (g == 0) ? x[p][1] : ((g == 1) ? 1.f : 0.f);
            B1[p] = cat4(cat2(cvt_pk(s[0], s[1]), cvt_pk(s[2], s[3])),
                         cat2(cvt_pk(s[4], s[5]), cvt_pk(v6, v7)));
        }

        // ---- layer 1, fused repack: acc(t1,p) -> quarter of B2 -----------
        f16x4_t h1q[2][4];
        #pragma unroll
        for (int t1 = 0; t1 < 4; ++t1)
            #pragma unroll
            for (int p = 0; p < 2; ++p) {
                floatx4 a = (floatx4){0.f, 0.f, 0.f, 0.f};
                a = __builtin_amdgcn_mfma_f32_16x16x32_f16(A1[t1], B1[p], a, 0, 0, 0);
                h1q[p][t1] = cat2(pk_relu(cvt_pk(a[0], a[1])),
                                  pk_relu(cvt_pk(a[2], a[3])));
            }
        f16x8 B2[2][2];
        #pragma unroll
        for (int p = 0; p < 2; ++p)
            #pragma unroll
            for (int kk = 0; kk < 2; ++kk)
                B2[p][kk] = cat4(h1q[p][2 * kk], h1q[p][2 * kk + 1]);

        // ---- layer 2, fused repack (+bias2 in packed f16) ----------------
        f16x4_t h2q[2][4];
        #pragma unroll
        for (int t2 = 0; t2 < 4; ++t2)
            #pragma unroll
            for (int p = 0; p < 2; ++p) {
                floatx4 a = (floatx4){0.f, 0.f, 0.f, 0.f};
                a = __builtin_amdgcn_mfma_f32_16x16x32_f16(A2[t2][0], B2[p][0], a, 0, 0, 0);
                a = __builtin_amdgcn_mfma_f32_16x16x32_f16(A2[t2][1], B2[p][1], a, 0, 0, 0);
                f16x2 lo = pk_relu(cvt_pk(a[0], a[1]) + b2pk[t2][0]);
                f16x2 hi = pk_relu(cvt_pk(a[2], a[3]) + b2pk[t2][1]);
                h2q[p][t2] = cat2(lo, hi);
            }
        f16x8 B3[2][2];
        #pragma unroll
        for (int p = 0; p < 2; ++p)
            #pragma unroll
            for (int kk = 0; kk < 2; ++kk)
                B3[p][kk] = cat4(h2q[p][2 * kk], h2q[p][2 * kk + 1]);

        // ---- layer 3 + store ---------------------------------------------
        #pragma unroll
        for (int p = 0; p < 2; ++p) {
            floatx4 acc3 = bias3q;
            #pragma unroll
            for (int kk = 0; kk < 2; ++kk)
                acc3 = __builtin_amdgcn_mfma_f32_16x16x32_f16(A3[kk], B3[p][kk], acc3, 0, 0, 0);
            if (g == 0)
                *reinterpret_cast<floatx4*>(&out[(long)(pbase + 16 * p + m) * 4]) = acc3;
        }
    }
}

extern "C" void kernel_launch(void* const* d_in, const int* in_sizes, int n_in,
                              void* d_out, int out_size, void* d_ws, size_t ws_size,
                              hipStream_t stream) {
    const float* coords = (const float*)d_in[0];
    const float* W1 = (const float*)d_in[1];
    const float* b1 = (const float*)d_in[2];
    const float* W2 = (const float*)d_in[3];
    const float* b2 = (const float*)d_in[4];
    const float* W3 = (const float*)d_in[5];
    const float* b3 = (const float*)d_in[6];
    float* outp = (float*)d_out;

    const int npts = in_sizes[0] / 3;           // 2,097,152
    const int nblocks = 2048;                   // 8192 waves; 65536 % 8192 == 0
    hipLaunchKernelGGL(nerf_fused_kernel, dim3(nblocks), dim3(256), 0, stream,
                       coords, W1, b1, W2, b2, W3, b3, outp, npts);
}

// Round 12
// 42.068 us; speedup vs baseline: 3.2044x; 1.0668x over previous
//
#include <hip/hip_runtime.h>

typedef _Float16 f16x2 __attribute__((ext_vector_type(2)));
typedef _Float16 f16x4_t __attribute__((ext_vector_type(4)));
typedef _Float16 f16x8 __attribute__((ext_vector_type(8)));
typedef float    floatx4 __attribute__((ext_vector_type(4)));

#define INV2PI 0.15915494309189535f

__device__ __forceinline__ f16x2 cvt_pk(float a, float b) {
    return __builtin_bit_cast(f16x2, __builtin_amdgcn_cvt_pkrtz(a, b));
}
__device__ __forceinline__ f16x2 pk_relu(f16x2 h) {
    f16x2 z; z[0] = (_Float16)0.f; z[1] = (_Float16)0.f;
    return __builtin_elementwise_max(h, z);       // v_pk_max_f16
}
__device__ __forceinline__ f16x4_t cat2(f16x2 a, f16x2 b) {
    return __builtin_shufflevector(a, b, 0, 1, 2, 3);
}
__device__ __forceinline__ f16x8 cat4(f16x4_t a, f16x4_t b) {
    return __builtin_shufflevector(a, b, 0, 1, 2, 3, 4, 5, 6, 7);
}

// N3R fused PE + 3-layer MLP.  Inputs f32 (harness upcast of f16 ref
// tensors), output f32.  One wave = TWO independent 16-point chains/iter;
// transposed layers D^T = W^T(A) @ act^T(B) via mfma_f32_16x16x32_f16;
// inter-layer transpose = fused static register repack (F-permutation).
// NEW: weight fragments live in LDS (fragment-linear, 1 ds_read_b128 each),
// staged once by wave 0 -> persistent VGPR set shrinks ~56 regs -> target
// 4 waves/SIMD.  An opaque-zero asm index defeats LICM re-hoisting.
__global__ __launch_bounds__(256, 4) void nerf_fused_kernel(
    const float* __restrict__ coords,
    const float* __restrict__ W1, const float* __restrict__ b1,
    const float* __restrict__ W2, const float* __restrict__ b2,
    const float* __restrict__ W3, const float* __restrict__ b3,
    float* __restrict__ out, int npts)
{
    // 14 fragments x 64 lanes x 16 B = 14 KB
    __shared__ __align__(16) floatx4 wlds[14][64];

    const int tid  = threadIdx.x;
    const int wave = tid >> 6;
    const int lane = tid & 63;
    const int m    = lane & 15;       // A row (out-feature) / B,D col (point)
    const int g    = lane >> 4;       // quarter-wave group (owns freq 2^g)

    // ---------------- stage weight fragments into LDS (wave 0) ------------
    // Layer-1 K-slot (g,i): i<6 -> enc feature 3+6g+3*(i>=3)+(i%3);
    // (0,6)=x0 (0,7)=x1 (1,6)=x2 (1,7)=bias row (enc==1); rest zero-pad.
    // F(kk, g*8+i) = ((i>>2)+2kk)*16 + g*4 + (i&3)  (D-layout-induced perm).
    if (wave == 0) {
        #pragma unroll
        for (int t1 = 0; t1 < 4; ++t1) {
            int n = t1 * 16 + m;
            f16x8 v;
            #pragma unroll
            for (int i = 0; i < 8; ++i) {
                float w;
                if (i < 6)        w = W1[(3 + 6 * g + (i >= 3 ? 3 : 0) + (i % 3)) * 64 + n];
                else if (g == 0)  w = (i == 6) ? W1[0 * 64 + n] : W1[1 * 64 + n];
                else if (g == 1)  w = (i == 6) ? W1[2 * 64 + n] : b1[n];
                else              w = 0.f;
                v[i] = (_Float16)w;
            }
            wlds[t1][lane] = __builtin_bit_cast(floatx4, v);
        }
        #pragma unroll
        for (int t2 = 0; t2 < 4; ++t2) {
            int n = t2 * 16 + m;
            #pragma unroll
            for (int kk = 0; kk < 2; ++kk) {
                f16x8 v;
                #pragma unroll
                for (int i = 0; i < 8; ++i) {
                    int f = ((i >> 2) + 2 * kk) * 16 + g * 4 + (i & 3);
                    v[i] = (_Float16)W2[f * 64 + n];
                }
                wlds[4 + t2 * 2 + kk][lane] = __builtin_bit_cast(floatx4, v);
            }
        }
        #pragma unroll
        for (int kk = 0; kk < 2; ++kk) {
            f16x8 v;
            #pragma unroll
            for (int i = 0; i < 8; ++i) {
                int f = ((i >> 2) + 2 * kk) * 16 + g * 4 + (i & 3);
                v[i] = (_Float16)((m < 4) ? W3[f * 4 + m] : 0.f);
            }
            wlds[12 + kk][lane] = __builtin_bit_cast(floatx4, v);
        }
    }
    __syncthreads();

    // bias2 packed f16 pairs; bias3 f32 (small persistent set)
    f16x2 b2pk[4][2];
    #pragma unroll
    for (int t2 = 0; t2 < 4; ++t2)
        #pragma unroll
        for (int h = 0; h < 2; ++h)
            b2pk[t2][h] = cvt_pk(b2[t2 * 16 + g * 4 + 2 * h],
                                 b2[t2 * 16 + g * 4 + 2 * h + 1]);
    floatx4 bias3q;
    #pragma unroll
    for (int r = 0; r < 4; ++r)
        bias3q[r] = (g == 0) ? b3[r] : 0.f;

    const float sg = __builtin_amdgcn_ldexpf(INV2PI, g);   // 2^g / (2*pi)

    // ---------------- main loop: 32 points (2 chains) per iteration -------
    const int nt32 = npts >> 5;                 // 65536 tiles
    const int gw   = blockIdx.x * 4 + wave;     // 8192 waves -> 8 iters/wave
    const int nw   = gridDim.x * 4;

    float cx[2][3];                             // prefetched coords
    {
        long nb = ((long)(gw << 5) + m) * 3;
        #pragma unroll
        for (int j = 0; j < 3; ++j) { cx[0][j] = coords[nb + j]; cx[1][j] = coords[nb + 48 + j]; }
    }

    for (int t32 = gw; t32 < nt32; t32 += nw) {
        const int pbase = t32 << 5;

        // opaque zero: weight loads become loop-variant -> no LICM hoist
        unsigned fr0 = 0;
        asm volatile("" : "+v"(fr0));
        const floatx4* wp = &wlds[0][0] + fr0 + lane;

        // ---- PE -> B1 fragments (consumes cx) ----------------------------
        f16x8 B1[2];
        #pragma unroll
        for (int p = 0; p < 2; ++p) {
            float s[6];
            #pragma unroll
            for (int i = 0; i < 6; ++i) {
                float xv = cx[p][i % 3];
                float ph = (i >= 3) ? 0.25f : 0.f;
                s[i] = __builtin_amdgcn_sinf(fmaf(xv, sg, ph));
            }
            float v6 = (g == 0) ? cx[p][0] : ((g == 1) ? cx[p][2] : 0.f);
            float v7 = (g == 0) ? cx[p][1] : ((g == 1) ? 1.f : 0.f);
            B1[p] = cat4(cat2(cvt_pk(s[0], s[1]), cvt_pk(s[2], s[3])),
                         cat2(cvt_pk(s[4], s[5]), cvt_pk(v6, v7)));
        }

        // ---- prefetch next tile's coords (cx free after PE) --------------
        {
            int tn = t32 + nw; if (tn >= nt32) tn = t32;   // clamped reload
            long nb = ((long)(tn << 5) + m) * 3;
            #pragma unroll
            for (int j = 0; j < 3; ++j) { cx[0][j] = coords[nb + j]; cx[1][j] = coords[nb + 48 + j]; }
        }

        // ---- layer 1, fused repack: acc(t1,p) -> quarter of B2 -----------
        f16x4_t h1q[2][4];
        #pragma unroll
        for (int t1 = 0; t1 < 4; ++t1) {
            f16x8 A1v = __builtin_bit_cast(f16x8, wp[t1 * 64]);
            #pragma unroll
            for (int p = 0; p < 2; ++p) {
                floatx4 a = (floatx4){0.f, 0.f, 0.f, 0.f};
                a = __builtin_amdgcn_mfma_f32_16x16x32_f16(A1v, B1[p], a, 0, 0, 0);
                h1q[p][t1] = cat2(pk_relu(cvt_pk(a[0], a[1])),
                                  pk_relu(cvt_pk(a[2], a[3])));
            }
        }
        f16x8 B2[2][2];
        #pragma unroll
        for (int p = 0; p < 2; ++p)
            #pragma unroll
            for (int kk = 0; kk < 2; ++kk)
                B2[p][kk] = cat4(h1q[p][2 * kk], h1q[p][2 * kk + 1]);

        // ---- layer 2, fused repack (+bias2 in packed f16) ----------------
        f16x4_t h2q[2][4];
        #pragma unroll
        for (int t2 = 0; t2 < 4; ++t2) {
            f16x8 A2v0 = __builtin_bit_cast(f16x8, wp[(4 + t2 * 2) * 64]);
            f16x8 A2v1 = __builtin_bit_cast(f16x8, wp[(5 + t2 * 2) * 64]);
            #pragma unroll
            for (int p = 0; p < 2; ++p) {
                floatx4 a = (floatx4){0.f, 0.f, 0.f, 0.f};
                a = __builtin_amdgcn_mfma_f32_16x16x32_f16(A2v0, B2[p][0], a, 0, 0, 0);
                a = __builtin_amdgcn_mfma_f32_16x16x32_f16(A2v1, B2[p][1], a, 0, 0, 0);
                f16x2 lo = pk_relu(cvt_pk(a[0], a[1]) + b2pk[t2][0]);
                f16x2 hi = pk_relu(cvt_pk(a[2], a[3]) + b2pk[t2][1]);
                h2q[p][t2] = cat2(lo, hi);
            }
        }
        f16x8 B3[2][2];
        #pragma unroll
        for (int p = 0; p < 2; ++p)
            #pragma unroll
            for (int kk = 0; kk < 2; ++kk)
                B3[p][kk] = cat4(h2q[p][2 * kk], h2q[p][2 * kk + 1]);

        // ---- layer 3 + store ---------------------------------------------
        f16x8 A3v0 = __builtin_bit_cast(f16x8, wp[12 * 64]);
        f16x8 A3v1 = __builtin_bit_cast(f16x8, wp[13 * 64]);
        #pragma unroll
        for (int p = 0; p < 2; ++p) {
            floatx4 acc3 = bias3q;
            acc3 = __builtin_amdgcn_mfma_f32_16x16x32_f16(A3v0, B3[p][0], acc3, 0, 0, 0);
            acc3 = __builtin_amdgcn_mfma_f32_16x16x32_f16(A3v1, B3[p][1], acc3, 0, 0, 0);
            if (g == 0)
                *reinterpret_cast<floatx4*>(&out[(long)(pbase + 16 * p + m) * 4]) = acc3;
        }
    }
}

extern "C" void kernel_launch(void* const* d_in, const int* in_sizes, int n_in,
                              void* d_out, int out_size, void* d_ws, size_t ws_size,
                              hipStream_t stream) {
    const float* coords = (const float*)d_in[0];
    const float* W1 = (const float*)d_in[1];
    const float* b1 = (const float*)d_in[2];
    const float* W2 = (const float*)d_in[3];
    const float* b2 = (const float*)d_in[4];
    const float* W3 = (const float*)d_in[5];
    const float* b3 = (const float*)d_in[6];
    float* outp = (float*)d_out;

    const int npts = in_sizes[0] / 3;           // 2,097,152
    const int nblocks = 2048;                   // 8192 waves; 65536 % 8192 == 0
    hipLaunchKernelGGL(nerf_fused_kernel, dim3(nblocks), dim3(256), 0, stream,
                       coords, W1, b1, W2, b2, W3, b3, outp, npts);
}

// Round 13
// 40.420 us; speedup vs baseline: 3.3350x; 1.0408x over previous
//
#include <hip/hip_runtime.h>

typedef _Float16 f16x2 __attribute__((ext_vector_type(2)));
typedef _Float16 f16x4_t __attribute__((ext_vector_type(4)));
typedef _Float16 f16x8 __attribute__((ext_vector_type(8)));
typedef float    floatx4 __attribute__((ext_vector_type(4)));

#define INV2PI 0.15915494309189535f
#define NP 4   // independent 16-point chains per wave-iteration

__device__ __forceinline__ f16x2 cvt_pk(float a, float b) {
    return __builtin_bit_cast(f16x2, __builtin_amdgcn_cvt_pkrtz(a, b));
}
__device__ __forceinline__ f16x2 pk_relu(f16x2 h) {
    f16x2 z; z[0] = (_Float16)0.f; z[1] = (_Float16)0.f;
    return __builtin_elementwise_max(h, z);       // v_pk_max_f16
}
__device__ __forceinline__ f16x4_t cat2(f16x2 a, f16x2 b) {
    return __builtin_shufflevector(a, b, 0, 1, 2, 3);
}
__device__ __forceinline__ f16x8 cat4(f16x4_t a, f16x4_t b) {
    return __builtin_shufflevector(a, b, 0, 1, 2, 3, 4, 5, 6, 7);
}

// N3R fused PE + 3-layer MLP.  Inputs f32 (harness upcast of f16 ref),
// output f32.  One wave = FOUR independent 16-point chains/iter (ILP);
// transposed layers D^T = W^T(A) @ act^T(B) via mfma_f32_16x16x32_f16;
// inter-layer transpose = fused static register repack (F-permutation).
// Weight fragments in LDS (fragment-linear, 1 conflict-free ds_read_b128
// each, re-read per iter; opaque-zero index defeats LICM re-hoisting).
__global__ __launch_bounds__(256, 4) void nerf_fused_kernel(
    const float* __restrict__ coords,
    const float* __restrict__ W1, const float* __restrict__ b1,
    const float* __restrict__ W2, const float* __restrict__ b2,
    const float* __restrict__ W3, const float* __restrict__ b3,
    float* __restrict__ out, int npts)
{
    // 14 fragments x 64 lanes x 16 B = 14 KB
    __shared__ __align__(16) floatx4 wlds[14][64];

    const int tid  = threadIdx.x;
    const int wave = tid >> 6;
    const int lane = tid & 63;
    const int m    = lane & 15;       // A row (out-feature) / B,D col (point)
    const int g    = lane >> 4;       // quarter-wave group (owns freq 2^g)

    // ---------------- stage weight fragments into LDS (wave 0) ------------
    // Layer-1 K-slot (g,i): i<6 -> enc feature 3+6g+3*(i>=3)+(i%3);
    // (0,6)=x0 (0,7)=x1 (1,6)=x2 (1,7)=bias row (enc==1); rest zero-pad.
    // F(kk, g*8+i) = ((i>>2)+2kk)*16 + g*4 + (i&3)  (D-layout-induced perm).
    if (wave == 0) {
        #pragma unroll
        for (int t1 = 0; t1 < 4; ++t1) {
            int n = t1 * 16 + m;
            f16x8 v;
            #pragma unroll
            for (int i = 0; i < 8; ++i) {
                float w;
                if (i < 6)        w = W1[(3 + 6 * g + (i >= 3 ? 3 : 0) + (i % 3)) * 64 + n];
                else if (g == 0)  w = (i == 6) ? W1[0 * 64 + n] : W1[1 * 64 + n];
                else if (g == 1)  w = (i == 6) ? W1[2 * 64 + n] : b1[n];
                else              w = 0.f;
                v[i] = (_Float16)w;
            }
            wlds[t1][lane] = __builtin_bit_cast(floatx4, v);
        }
        #pragma unroll
        for (int t2 = 0; t2 < 4; ++t2) {
            int n = t2 * 16 + m;
            #pragma unroll
            for (int kk = 0; kk < 2; ++kk) {
                f16x8 v;
                #pragma unroll
                for (int i = 0; i < 8; ++i) {
                    int f = ((i >> 2) + 2 * kk) * 16 + g * 4 + (i & 3);
                    v[i] = (_Float16)W2[f * 64 + n];
                }
                wlds[4 + t2 * 2 + kk][lane] = __builtin_bit_cast(floatx4, v);
            }
        }
        #pragma unroll
        for (int kk = 0; kk < 2; ++kk) {
            f16x8 v;
            #pragma unroll
            for (int i = 0; i < 8; ++i) {
                int f = ((i >> 2) + 2 * kk) * 16 + g * 4 + (i & 3);
                v[i] = (_Float16)((m < 4) ? W3[f * 4 + m] : 0.f);
            }
            wlds[12 + kk][lane] = __builtin_bit_cast(floatx4, v);
        }
    }
    __syncthreads();

    // bias2 packed f16 pairs; bias3 f32 (small persistent set)
    f16x2 b2pk[4][2];
    #pragma unroll
    for (int t2 = 0; t2 < 4; ++t2)
        #pragma unroll
        for (int h = 0; h < 2; ++h)
            b2pk[t2][h] = cvt_pk(b2[t2 * 16 + g * 4 + 2 * h],
                                 b2[t2 * 16 + g * 4 + 2 * h + 1]);
    floatx4 bias3q;
    #pragma unroll
    for (int r = 0; r < 4; ++r)
        bias3q[r] = (g == 0) ? b3[r] : 0.f;

    const float sg = __builtin_amdgcn_ldexpf(INV2PI, g);   // 2^g / (2*pi)

    // ---------------- main loop: 64 points (4 chains) per iteration -------
    const int ntile = npts >> (4 + 2);          // 32768 tiles of 64 pts
    const int gw    = blockIdx.x * 4 + wave;    // 8192 waves -> 4 iters/wave
    const int nw    = gridDim.x * 4;

    float cx[NP][3];                            // prefetched coords
    {
        long nb = ((long)(gw << 6) + m) * 3;
        #pragma unroll
        for (int p = 0; p < NP; ++p)
            #pragma unroll
            for (int j = 0; j < 3; ++j) cx[p][j] = coords[nb + 48 * p + j];
    }

    for (int tt = gw; tt < ntile; tt += nw) {
        const int pbase = tt << 6;

        // opaque zero: weight loads become loop-variant -> no LICM hoist
        unsigned fr0 = 0;
        asm volatile("" : "+v"(fr0));
        const floatx4* wp = &wlds[0][0] + fr0 + lane;

        // ---- PE -> B1 fragments (consumes cx) ----------------------------
        f16x8 B1[NP];
        #pragma unroll
        for (int p = 0; p < NP; ++p) {
            float s[6];
            #pragma unroll
            for (int i = 0; i < 6; ++i) {
                float xv = cx[p][i % 3];
                float ph = (i >= 3) ? 0.25f : 0.f;
                s[i] = __builtin_amdgcn_sinf(fmaf(xv, sg, ph));
            }
            float v6 = (g == 0) ? cx[p][0] : ((g == 1) ? cx[p][2] : 0.f);
            float v7 = (g == 0) ? cx[p][1] : ((g == 1) ? 1.f : 0.f);
            B1[p] = cat4(cat2(cvt_pk(s[0], s[1]), cvt_pk(s[2], s[3])),
                         cat2(cvt_pk(s[4], s[5]), cvt_pk(v6, v7)));
        }

        // ---- prefetch next tile's coords (cx free after PE) --------------
        {
            int tn = tt + nw; if (tn >= ntile) tn = tt;    // clamped reload
            long nb = ((long)(tn << 6) + m) * 3;
            #pragma unroll
            for (int p = 0; p < NP; ++p)
                #pragma unroll
                for (int j = 0; j < 3; ++j) cx[p][j] = coords[nb + 48 * p + j];
        }

        // ---- layer 1, fused repack: acc(t1,p) -> quarter of B2 -----------
        f16x4_t h1q[NP][4];
        #pragma unroll
        for (int t1 = 0; t1 < 4; ++t1) {
            f16x8 A1v = __builtin_bit_cast(f16x8, wp[t1 * 64]);
            #pragma unroll
            for (int p = 0; p < NP; ++p) {
                floatx4 a = (floatx4){0.f, 0.f, 0.f, 0.f};
                a = __builtin_amdgcn_mfma_f32_16x16x32_f16(A1v, B1[p], a, 0, 0, 0);
                h1q[p][t1] = cat2(pk_relu(cvt_pk(a[0], a[1])),
                                  pk_relu(cvt_pk(a[2], a[3])));
            }
        }
        f16x8 B2[NP][2];
        #pragma unroll
        for (int p = 0; p < NP; ++p)
            #pragma unroll
            for (int kk = 0; kk < 2; ++kk)
                B2[p][kk] = cat4(h1q[p][2 * kk], h1q[p][2 * kk + 1]);

        // ---- layer 2, fused repack (+bias2 in packed f16) ----------------
        f16x4_t h2q[NP][4];
        #pragma unroll
        for (int t2 = 0; t2 < 4; ++t2) {
            f16x8 A2v0 = __builtin_bit_cast(f16x8, wp[(4 + t2 * 2) * 64]);
            f16x8 A2v1 = __builtin_bit_cast(f16x8, wp[(5 + t2 * 2) * 64]);
            #pragma unroll
            for (int p = 0; p < NP; ++p) {
                floatx4 a = (floatx4){0.f, 0.f, 0.f, 0.f};
                a = __builtin_amdgcn_mfma_f32_16x16x32_f16(A2v0, B2[p][0], a, 0, 0, 0);
                a = __builtin_amdgcn_mfma_f32_16x16x32_f16(A2v1, B2[p][1], a, 0, 0, 0);
                f16x2 lo = pk_relu(cvt_pk(a[0], a[1]) + b2pk[t2][0]);
                f16x2 hi = pk_relu(cvt_pk(a[2], a[3]) + b2pk[t2][1]);
                h2q[p][t2] = cat2(lo, hi);
            }
        }
        f16x8 B3[NP][2];
        #pragma unroll
        for (int p = 0; p < NP; ++p)
            #pragma unroll
            for (int kk = 0; kk < 2; ++kk)
                B3[p][kk] = cat4(h2q[p][2 * kk], h2q[p][2 * kk + 1]);

        // ---- layer 3 + store ---------------------------------------------
        f16x8 A3v0 = __builtin_bit_cast(f16x8, wp[12 * 64]);
        f16x8 A3v1 = __builtin_bit_cast(f16x8, wp[13 * 64]);
        #pragma unroll
        for (int p = 0; p < NP; ++p) {
            floatx4 acc3 = bias3q;
            acc3 = __builtin_amdgcn_mfma_f32_16x16x32_f16(A3v0, B3[p][0], acc3, 0, 0, 0);
            acc3 = __builtin_amdgcn_mfma_f32_16x16x32_f16(A3v1, B3[p][1], acc3, 0, 0, 0);
            if (g == 0)
                *reinterpret_cast<floatx4*>(&out[(long)(pbase + 16 * p + m) * 4]) = acc3;
        }
    }
}

extern "C" void kernel_launch(void* const* d_in, const int* in_sizes, int n_in,
                              void* d_out, int out_size, void* d_ws, size_t ws_size,
                              hipStream_t stream) {
    const float* coords = (const float*)d_in[0];
    const float* W1 = (const float*)d_in[1];
    const float* b1 = (const float*)d_in[2];
    const float* W2 = (const float*)d_in[3];
    const float* b2 = (const float*)d_in[4];
    const float* W3 = (const float*)d_in[5];
    const float* b3 = (const float*)d_in[6];
    float* outp = (float*)d_out;

    const int npts = in_sizes[0] / 3;           // 2,097,152
    const int nblocks = 2048;                   // 8192 waves; 32768 % 8192 == 0
    hipLaunchKernelGGL(nerf_fused_kernel, dim3(nblocks), dim3(256), 0, stream,
                       coords, W1, b1, W2, b2, W3, b3, outp, npts);
}